// Round 13
// baseline (309.062 us; speedup 1.0000x reference)
//
#include <hip/hip_runtime.h>
#include <hip/hip_fp16.h>
#include <math.h>

// R7: radix CSR build. R12: fp16 gather table. R13: MFMA GEMM. R16/R17:
// 16-lanes/node aggregate + 32-deep ILP (fabric ceiling: 205MB/33us).
// R19: logits->pool fusion. R20: pool 1024thr. R21: group counting sort.
// R22 FAILED: fp8 gather absmax 2.8e-5 > threshold 2.75e-6 (threshold now
// KNOWN ~2.7e-6; fp16 margin is only 3x -> precision is off the table).
// R23 (this round): revert to fp16 (R21 state) + remove bucket_scan_kernel
// (single-block = 1-CU serialization + 2 launch gaps). group_kernel scans
// btot alongside its existing hist-column scan; bucket_build computes its
// bucket base by strided sum of btot. 12 launches -> 11, numerics untouched.

#define BKT_SHIFT 7
#define BKT_NODES 128
#define BKT_CAP 4096   // LDS staging cap; overflow -> direct-write fallback
#define EPB 8192       // edges per block; == group stage capacity (exact)

typedef _Float16 f16x8 __attribute__((ext_vector_type(8)));
typedef float f32x4 __attribute__((ext_vector_type(4)));

// ---------------- phase A: per-(bucket,block) histogram ----------------
__global__ __launch_bounds__(1024) void block_hist_kernel(
    const int* __restrict__ dst, int* __restrict__ hist, int E, int NBKT, int NBLK) {
  __shared__ int lh[1024];  // >= NBKT
  const int t = threadIdx.x;
  const int blk = blockIdx.x;
  for (int k = t; k < NBKT; k += 1024) lh[k] = 0;
  __syncthreads();
  const int e0 = blk * EPB;
  const int e1 = min(e0 + EPB, E);
  for (int e = e0 + t; e < e1; e += 1024) atomicAdd(&lh[dst[e] >> BKT_SHIFT], 1);
  __syncthreads();
  for (int k = t; k < NBKT; k += 1024) hist[k * NBLK + blk] = lh[k];
}

// ---------------- phase B: per-bucket row scan (grid-parallel) ----------
__global__ __launch_bounds__(256) void row_scan_kernel(
    const int* __restrict__ hist, int* __restrict__ ebase, int* __restrict__ btot,
    int NBLK) {
  __shared__ int sh[256];
  const int k = blockIdx.x;
  const int t = threadIdx.x;
  int v = (t < NBLK) ? hist[(long)k * NBLK + t] : 0;
  sh[t] = v;
  __syncthreads();
  for (int s = 1; s < 256; s <<= 1) {
    int add = (t >= s) ? sh[t - s] : 0;
    __syncthreads();
    sh[t] += add;
    __syncthreads();
  }
  if (t < NBLK) ebase[(long)k * NBLK + t] = sh[t] - v;  // row-local exclusive
  if (t == 255) btot[k] = sh[255];
}

// ------- phase C: group edges by bucket (LDS counting sort + runs) -------
// Scans BOTH its hist column (block-local offsets) and btot (global bucket
// bases) in one LDS pass -- bucket_scan_kernel eliminated (was a 1-block
// serialization point). Flush: 16-lane subgroups -> consecutive addresses.
__global__ __launch_bounds__(1024) void group_kernel(
    const int* __restrict__ src, const int* __restrict__ dst,
    const int* __restrict__ btot, const int* __restrict__ ebase,
    const int* __restrict__ hist, unsigned int* __restrict__ grouped,
    int E, int NBKT, int NBLK) {
  __shared__ int lsum[1024];
  __shared__ int gsum[1024];
  __shared__ int lbase[1024];
  __shared__ int gbase[1024];
  __shared__ int lcur[1024];
  __shared__ unsigned int stage[EPB];   // 32KB; per-block edges <= EPB exact
  const int t = threadIdx.x;
  const int blk = blockIdx.x;

  int v = (t < NBKT) ? hist[(long)t * NBLK + blk] : 0;
  int w = (t < NBKT) ? btot[t] : 0;
  lsum[t] = v;
  gsum[t] = w;
  __syncthreads();
  for (int s = 1; s < 1024; s <<= 1) {
    int addl = (t >= s) ? lsum[t - s] : 0;
    int addg = (t >= s) ? gsum[t - s] : 0;
    __syncthreads();
    lsum[t] += addl;
    gsum[t] += addg;
    __syncthreads();
  }
  if (t < NBKT) {
    lbase[t] = lsum[t] - v;
    lcur[t] = lsum[t] - v;
    gbase[t] = gsum[t] - w;     // global exclusive bucket base
  }
  __syncthreads();

  const int e0 = blk * EPB;
  const int e1 = min(e0 + EPB, E);
  for (int e = e0 + t; e < e1; e += 1024) {
    int d = dst[e];
    int k = d >> BKT_SHIFT;
    int p = atomicAdd(&lcur[k], 1);
    stage[p] = ((unsigned int)(d & (BKT_NODES - 1)) << 17) | (unsigned int)src[e];
  }
  __syncthreads();

  const int sg = t >> 4;
  const int l16 = t & 15;
  for (int k = sg; k < NBKT; k += 64) {
    const int lb = lbase[k];
    const int L = lcur[k] - lb;
    if (L == 0) continue;
    const long gb = (long)gbase[k] + ebase[(long)k * NBLK + blk];
    for (int off = l16; off < L; off += 16)
      grouped[gb + off] = stage[lb + off];
  }
}

// ---------------- phase D: per-bucket CSR finalize + ends + dis ----------
// Computes its own bucket base = sum(btot[0..b-1]) (256-thr strided sum);
// m = btot[b]. bucket_scan's bbase array no longer exists.
__global__ __launch_bounds__(256) void bucket_build_kernel(
    const unsigned int* __restrict__ grouped, const int* __restrict__ btot,
    int* __restrict__ csr_src, int* __restrict__ ends, float* __restrict__ dis, int N) {
  __shared__ int lcnt[BKT_NODES];
  __shared__ int lsum[BKT_NODES];
  __shared__ int lcur[BKT_NODES];
  __shared__ int red[256];
  __shared__ int stage[BKT_CAP];
  const int b = blockIdx.x;
  const int t = threadIdx.x;
  const int node0 = b << BKT_SHIFT;
  const int nn = min(BKT_NODES, N - node0);

  // base = exclusive sum of btot up to b (btot is L2-hot, 782 ints)
  int part = 0;
  for (int i = t; i < b; i += 256) part += btot[i];
  red[t] = part;
  __syncthreads();
  for (int s = 128; s > 0; s >>= 1) {
    if (t < s) red[t] += red[t + s];
    __syncthreads();
  }
  const int base = red[0];
  const int m = btot[b];

  if (t < BKT_NODES) lcnt[t] = 0;
  __syncthreads();
  for (int i = t; i < m; i += 256) atomicAdd(&lcnt[grouped[base + i] >> 17], 1);
  __syncthreads();
  if (t < BKT_NODES) lsum[t] = lcnt[t];
  __syncthreads();
  for (int s = 1; s < BKT_NODES; s <<= 1) {
    int add = 0;
    if (t < BKT_NODES && t >= s) add = lsum[t - s];
    __syncthreads();
    if (t < BKT_NODES) lsum[t] += add;
    __syncthreads();
  }
  if (t < nn) {
    ends[node0 + t] = base + lsum[t];                      // global inclusive end
    dis[node0 + t] = 1.0f / sqrtf((float)(lcnt[t] + 1));   // +1 self loop
    lcur[t] = lsum[t] - lcnt[t];                           // local exclusive cursor
  }
  __syncthreads();
  if (m <= BKT_CAP) {
    for (int i = t; i < m; i += 256) {
      unsigned int v = grouped[base + i];
      int p = atomicAdd(&lcur[v >> 17], 1);
      stage[p] = (int)(v & 0x1FFFFu);
    }
    __syncthreads();
    for (int i = t; i < m; i += 256) csr_src[base + i] = stage[i];
  } else {  // statistically never; correctness fallback
    for (int i = t; i < m; i += 256) {
      unsigned int v = grouped[base + i];
      int p = atomicAdd(&lcur[v >> 17], 1);
      csr_src[base + p] = (int)(v & 0x1FFFFu);
    }
  }
}

// ------- MFMA GEMM: C[N,64] = fp16( (H[N,K] @ W[K,64]) * dis[row] ) -----
// 64 rows/block, 256 thr = 4 waves; wave w owns rows 16w..16w+15.
// Whole K staged: Hs[64][K] fp16, Ws[64][K] fp16 (= W^T), both XOR-swizzled.

template <int K, typename Tin>
__global__ __launch_bounds__(256) void gemm_mfma_kernel(
    const Tin* __restrict__ H, const float* __restrict__ W,
    const float* __restrict__ dis, __half* __restrict__ C, int N) {
  __shared__ __align__(16) __half Hs[64 * K];
  __shared__ __align__(16) __half Ws[64 * K];
  const int t = threadIdx.x;
  const int rowBase = blockIdx.x * 64;

  // ---- stage H (cast to fp16, swizzled) ----
  if constexpr (sizeof(Tin) == 4) {
    const int NF4 = 64 * K / 4;
#pragma unroll
    for (int i = 0; i < NF4 / 256; ++i) {
      int f = t + i * 256;
      int row = f / (K / 4);
      int c4 = f % (K / 4);
      int gr = rowBase + row;
      float4 v = make_float4(0.f, 0.f, 0.f, 0.f);
      if (gr < N) v = *reinterpret_cast<const float4*>(H + (long)gr * K + c4 * 4);
      union { uint2 u; __half2 h[2]; } pk;
      pk.h[0] = __floats2half2_rn(v.x, v.y);
      pk.h[1] = __floats2half2_rn(v.z, v.w);
      int byte = (row * K + c4 * 4) * 2;
      byte ^= (row & 7) << 4;
      *reinterpret_cast<uint2*>(reinterpret_cast<char*>(Hs) + byte) = pk.u;
    }
  } else {
    const int NC = 64 * K / 8;
#pragma unroll
    for (int i = 0; i < NC / 256; ++i) {
      int f = t + i * 256;
      int row = f / (K / 8);
      int c8 = f % (K / 8);
      int gr = rowBase + row;
      uint4 v = make_uint4(0u, 0u, 0u, 0u);
      if (gr < N) v = *reinterpret_cast<const uint4*>(H + (long)gr * K + c8 * 8);
      int byte = (row * K + c8 * 8) * 2;
      byte ^= (row & 7) << 4;
      *reinterpret_cast<uint4*>(reinterpret_cast<char*>(Hs) + byte) = v;
    }
  }

  // ---- stage W^T (transpose via half2 k-pairs, swizzled) ----
  {
    const int NU = (K / 2) * 16;  // (k-pair, col-quad) units
#pragma unroll
    for (int i = 0; i < NU / 256; ++i) {
      int u = t + i * 256;
      int kp = u >> 4;
      int cq = u & 15;
      const float4 w0 = *reinterpret_cast<const float4*>(W + (long)(2 * kp) * 64 + cq * 4);
      const float4 w1 = *reinterpret_cast<const float4*>(W + (long)(2 * kp + 1) * 64 + cq * 4);
#pragma unroll
      for (int j = 0; j < 4; ++j) {
        int c = cq * 4 + j;
        __half2 p = __floats2half2_rn((&w0.x)[j], (&w1.x)[j]);
        int byte = (c * K + 2 * kp) * 2;
        byte ^= (c & 7) << 4;
        *reinterpret_cast<__half2*>(reinterpret_cast<char*>(Ws) + byte) = p;
      }
    }
  }
  __syncthreads();

  // ---- MFMA: wave computes 16 rows x 64 cols ----
  const int w = t >> 6;
  const int l = t & 63;
  const int r = l & 15;
  const int g = l >> 4;
  const int rowL = 16 * w + r;
  f32x4 acc[4] = {{0.f, 0.f, 0.f, 0.f}, {0.f, 0.f, 0.f, 0.f},
                  {0.f, 0.f, 0.f, 0.f}, {0.f, 0.f, 0.f, 0.f}};
#pragma unroll
  for (int s = 0; s < K / 32; ++s) {
    int abyte = (rowL * K + s * 32 + g * 8) * 2;
    abyte ^= (rowL & 7) << 4;
    f16x8 afrag = *reinterpret_cast<const f16x8*>(reinterpret_cast<const char*>(Hs) + abyte);
#pragma unroll
    for (int n = 0; n < 4; ++n) {
      int col = n * 16 + r;
      int bbyte = (col * K + s * 32 + g * 8) * 2;
      bbyte ^= (col & 7) << 4;
      f16x8 bfrag = *reinterpret_cast<const f16x8*>(reinterpret_cast<const char*>(Ws) + bbyte);
      acc[n] = __builtin_amdgcn_mfma_f32_16x16x32_f16(afrag, bfrag, acc[n], 0, 0, 0);
    }
  }

  // ---- epilogue: scale by dis[row], round to fp16 ----
  const int outRow0 = rowBase + 16 * w + 4 * g;
#pragma unroll
  for (int j = 0; j < 4; ++j) {
    int row = outRow0 + j;
    if (row < N) {
      float dv = dis[row];
#pragma unroll
      for (int n = 0; n < 4; ++n) {
        C[(long)row * 64 + n * 16 + r] = __float2half(acc[n][j] * dv);
      }
    }
  }
}

// -------- aggregation: CSR, 16 lanes/node, 4 nodes/wave, deep ILP --------
// Lane (g,c) owns cols 4c..4c+3 of node d=wid*4+g. Chunks 0+1 (32 edges)
// fully staged: idx prefetched, 32 row-loads issued before ANY accumulate
// (pad lanes clamp to row d = L1-hot). Dynamic tail for degree>32 only.

__device__ __forceinline__ float4 h4_to_f4(uint2 u) {
  const __half2 lo = *reinterpret_cast<const __half2*>(&u.x);
  const __half2 hi = *reinterpret_cast<const __half2*>(&u.y);
  const float2 flo = __half22float2(lo);
  const float2 fhi = __half22float2(hi);
  return make_float4(flo.x, flo.y, fhi.x, fhi.y);
}

__global__ __launch_bounds__(256) void aggregate_kernel(
    const __half* __restrict__ Ts, const int* __restrict__ csr_src,
    const int* __restrict__ ends, const float* __restrict__ dis,
    const float* __restrict__ bias, __half* __restrict__ O, int N) {
  const int wid = (blockIdx.x * 256 + threadIdx.x) >> 6;
  const int l = threadIdx.x & 63;
  const int g = l >> 4;         // node within wave quad
  const int c = l & 15;         // uint2 column of the 128B row
  const int d0 = wid * 4 + g;
  const bool valid = d0 < N;
  const int d = valid ? d0 : (N - 1);   // safe row for pad lanes
  const int beg = valid ? ((d0 == 0) ? 0 : ends[d0 - 1]) : 0;
  const int m = valid ? (ends[d0] - beg) : 0;   // group-uniform per valid group
  const uint2* Tv = (const uint2*)Ts;

  // self loop (pre-scaled by dis[d])
  float4 a = h4_to_f4(Tv[(long)d * 16 + c]);

  // wave-uniform outer trip count so shfl stays convergent
  int mmax = m;
  mmax = max(mmax, __shfl_xor(mmax, 16, 64));
  mmax = max(mmax, __shfl_xor(mmax, 32, 64));

  const int gbase = l & 48;     // first lane of this group

  // ---- prefetch indices for chunks 0 and 1 ----
  int idx0 = (c < m) ? csr_src[beg + c] : 0;
  int idx1 = (16 + c < m) ? csr_src[beg + 16 + c] : 0;

  // ---- stage all 32 row loads before accumulating ----
  uint2 fr0[16], fr1[16];
  const bool has0 = (mmax > 0), has1 = (mmax > 16);
  if (has0) {
#pragma unroll
    for (int j = 0; j < 16; ++j) {
      int s = __shfl(idx0, gbase + j, 64);
      s = (j < m) ? s : d;              // pad -> own row (L1-hot)
      fr0[j] = Tv[(long)s * 16 + c];
    }
  }
  if (has1) {
#pragma unroll
    for (int j = 0; j < 16; ++j) {
      int s = __shfl(idx1, gbase + j, 64);
      s = (j + 16 < m) ? s : d;
      fr1[j] = Tv[(long)s * 16 + c];
    }
  }
  if (has0) {
#pragma unroll
    for (int j = 0; j < 16; ++j) {
      if (j < m) {
        float4 f = h4_to_f4(fr0[j]);
        a.x += f.x; a.y += f.y; a.z += f.z; a.w += f.w;
      }
    }
  }
  if (has1) {
#pragma unroll
    for (int j = 0; j < 16; ++j) {
      if (j + 16 < m) {
        float4 f = h4_to_f4(fr1[j]);
        a.x += f.x; a.y += f.y; a.z += f.z; a.w += f.w;
      }
    }
  }

  // ---- dynamic tail (degree > 32; Poisson(16) => rare) ----
  for (int base = 32; base < mmax; base += 16) {
    const int take = m - base;
    int idx = (base + c < m) ? csr_src[beg + base + c] : 0;
    uint2 fr[16];
#pragma unroll
    for (int j = 0; j < 16; ++j) {
      int s = __shfl(idx, gbase + j, 64);
      s = (j < take) ? s : d;
      fr[j] = Tv[(long)s * 16 + c];
    }
#pragma unroll
    for (int j = 0; j < 16; ++j) {
      if (j < take) {
        float4 f = h4_to_f4(fr[j]);
        a.x += f.x; a.y += f.y; a.z += f.z; a.w += f.w;
      }
    }
  }

  if (valid) {
    const float dd = dis[d0];
    const float4 b4 = ((const float4*)bias)[c];
    union { uint2 uu; __half2 h[2]; } pk;
    pk.h[0] = __floats2half2_rn(fmaxf(a.x * dd + b4.x, 0.f),
                                fmaxf(a.y * dd + b4.y, 0.f));
    pk.h[1] = __floats2half2_rn(fmaxf(a.z * dd + b4.z, 0.f),
                                fmaxf(a.w * dd + b4.w, 0.f));
    ((uint2*)O)[(long)d0 * 16 + c] = pk.uu;
  }
}

// -------- pooling (logits fused, 1024 thr = 16 waves for latency) --------

__global__ __launch_bounds__(1024) void pool_kernel(
    const __half* __restrict__ h3, const float* __restrict__ clo,
    const float* __restrict__ Wc, const float* __restrict__ bc,
    const int* __restrict__ batch, const float* __restrict__ Wa1,
    const float* __restrict__ ba1, const float* __restrict__ Wa2,
    const float* __restrict__ ba2, float* __restrict__ out, int N) {
  __shared__ int sLo, sHi;
  __shared__ float red[1024];
  __shared__ float Vs[16][64];
  __shared__ float sse[16];
  __shared__ float gv[64];
  __shared__ float am[16];
  const int g = blockIdx.x;
  const int t = threadIdx.x;
  if (t == 0) {
    int lo = 0, hi = N;
    while (lo < hi) { int mid = (lo + hi) >> 1; if (batch[mid] < g) lo = mid + 1; else hi = mid; }
    sLo = lo;
    lo = 0; hi = N;
    while (lo < hi) { int mid = (lo + hi) >> 1; if (batch[mid] < g + 1) lo = mid + 1; else hi = mid; }
    sHi = lo;
  }
  __syncthreads();
  const int lo = sLo, hi = sHi;

  // logits computed inline: lb(i) = dot(clo[i,0:8], Wc) + bc
  float wc[8];
#pragma unroll
  for (int k = 0; k < 8; ++k) wc[k] = Wc[k];
  const float bc0 = bc[0];

  float lm = -1e30f;
  for (int i = lo + t; i < hi; i += 1024) {
    const float4 c0 = *reinterpret_cast<const float4*>(clo + (long)i * 8);
    const float4 c1 = *reinterpret_cast<const float4*>(clo + (long)i * 8 + 4);
    float s = bc0 + c0.x * wc[0] + c0.y * wc[1] + c0.z * wc[2] + c0.w * wc[3]
                  + c1.x * wc[4] + c1.y * wc[5] + c1.z * wc[6] + c1.w * wc[7];
    lm = fmaxf(lm, s);
  }
  red[t] = lm;
  __syncthreads();
  for (int s = 512; s > 0; s >>= 1) {
    if (t < s) red[t] = fmaxf(red[t], red[t + s]);
    __syncthreads();
  }
  const float m = red[0];

  const int f = t & 63, sub = t >> 6;   // 16 sub-groups of one wave each
  float vacc = 0.f, seacc = 0.f;
  for (int i = lo + sub; i < hi; i += 16) {
    const float4 c0 = *reinterpret_cast<const float4*>(clo + (long)i * 8);
    const float4 c1 = *reinterpret_cast<const float4*>(clo + (long)i * 8 + 4);
    float s = bc0 + c0.x * wc[0] + c0.y * wc[1] + c0.z * wc[2] + c0.w * wc[3]
                  + c1.x * wc[4] + c1.y * wc[5] + c1.z * wc[6] + c1.w * wc[7];
    float e = expf(s - m);
    seacc += e;
    vacc += e * __half2float(h3[(long)i * 64 + f]);
  }
  Vs[sub][f] = vacc;
  if (f == 0) sse[sub] = seacc;
  __syncthreads();
  if (t < 64) {
    float se = 0.f, v = 0.f;
#pragma unroll
    for (int s2 = 0; s2 < 16; ++s2) { se += sse[s2]; v += Vs[s2][f]; }
    gv[f] = (se > 0.f) ? v / se : 0.f;
  }
  __syncthreads();
  if (t < 16) {
    float a = ba1[t];
#pragma unroll
    for (int k2 = 0; k2 < 64; ++k2) a += gv[k2] * Wa1[k2 * 16 + t];
    am[t] = a > 0.f ? a : 0.f;
  }
  __syncthreads();
  if (t == 0) {
    float o = ba2[0];
#pragma unroll
    for (int j = 0; j < 16; ++j) o += am[j] * Wa2[j];
    out[g] = o;
  }
}

// ---------------- launcher ----------------

extern "C" void kernel_launch(void* const* d_in, const int* in_sizes, int n_in,
                              void* d_out, int out_size, void* d_ws, size_t ws_size,
                              hipStream_t stream) {
  const float* x   = (const float*)d_in[0];
  const float* clo = (const float*)d_in[1];
  const float* W1  = (const float*)d_in[2];
  const float* b1  = (const float*)d_in[3];
  const float* W2  = (const float*)d_in[4];
  const float* b2  = (const float*)d_in[5];
  const float* W3  = (const float*)d_in[6];
  const float* b3  = (const float*)d_in[7];
  const float* Wc  = (const float*)d_in[8];
  const float* bc  = (const float*)d_in[9];
  const float* Wa1 = (const float*)d_in[10];
  const float* ba1 = (const float*)d_in[11];
  const float* Wa2 = (const float*)d_in[12];
  const float* ba2 = (const float*)d_in[13];
  const int* edge  = (const int*)d_in[14];
  const int* batch = (const int*)d_in[15];
  float* out = (float*)d_out;

  const int N = in_sizes[15];        // 100000
  const int E = in_sizes[14] / 2;    // 1600000
  const int G = out_size;            // 256
  const int NBKT = (N + BKT_NODES - 1) >> BKT_SHIFT;  // 782 (<=1024)
  const int NBLK = (E + EPB - 1) / EPB;               // 196 (<=256)

  const int* src = edge;
  const int* dst = edge + E;

  char* p = (char*)d_ws;
  auto alloc = [&](size_t bytes) -> char* {
    char* r = p;
    p += (bytes + 255) & ~(size_t)255;
    return r;
  };
  __half* tsbuf         = (__half*)alloc((size_t)N * 64 * sizeof(__half));
  __half* bufH          = (__half*)alloc((size_t)N * 64 * sizeof(__half));
  int*   csr_src        = (int*)  alloc((size_t)E * sizeof(int));
  unsigned int* grouped = (unsigned int*)alloc((size_t)E * sizeof(unsigned int));
  int*   hist           = (int*)  alloc((size_t)NBKT * NBLK * sizeof(int));
  int*   ebase          = (int*)  alloc((size_t)NBKT * NBLK * sizeof(int));
  int*   btot           = (int*)  alloc((size_t)NBKT * sizeof(int));
  int*   ends           = (int*)  alloc((size_t)N * sizeof(int));
  float* dis            = (float*)alloc((size_t)N * sizeof(float));
  (void)ws_size; (void)n_in;

  block_hist_kernel<<<NBLK, 1024, 0, stream>>>(dst, hist, E, NBKT, NBLK);
  row_scan_kernel<<<NBKT, 256, 0, stream>>>(hist, ebase, btot, NBLK);
  group_kernel<<<NBLK, 1024, 0, stream>>>(src, dst, btot, ebase, hist, grouped, E, NBKT, NBLK);
  bucket_build_kernel<<<NBKT, 256, 0, stream>>>(grouped, btot, csr_src, ends, dis, N);

  const int gGemm = (N + 63) / 64;
  const int gAgg  = (N + 15) / 16;   // 16 nodes per 256-thread block

  gemm_mfma_kernel<128, float><<<gGemm, 256, 0, stream>>>(x, W1, dis, tsbuf, N);
  aggregate_kernel<<<gAgg, 256, 0, stream>>>(tsbuf, csr_src, ends, dis, b1, bufH, N);
  gemm_mfma_kernel<64, __half><<<gGemm, 256, 0, stream>>>(bufH, W2, dis, tsbuf, N);
  aggregate_kernel<<<gAgg, 256, 0, stream>>>(tsbuf, csr_src, ends, dis, b2, bufH, N);
  gemm_mfma_kernel<64, __half><<<gGemm, 256, 0, stream>>>(bufH, W3, dis, tsbuf, N);
  aggregate_kernel<<<gAgg, 256, 0, stream>>>(tsbuf, csr_src, ends, dis, b3, bufH, N);

  pool_kernel<<<G, 1024, 0, stream>>>(bufH, clo, Wc, bc, batch, Wa1, ba1, Wa2, ba2, out, N);
}